// Round 3
// baseline (115.511 us; speedup 1.0000x reference)
//
#include <hip/hip_runtime.h>

#define BB 2
#define LL 24
#define RR 8
#define CC 32
#define HH 48
#define WF 49
#define HW (HH*WF)            // 2352
#define HALF (HW/2)           // 1176 = 24*49  (same w phase as lower half)
#define ASLAB (RR*CC*WF)      // 12544  (A elements per (b,l))
#define SLAB (RR*CC*HH*WF)    // 602112 (u elements per (b,l))
#define OUT_HALF (BB*LL*SLAB) // 28901376
#define QG (HALF/4)           // 294 four-wide groups per (b,rc) half-plane
#define NTH (BB*RR*CC*QG)     // 150528 threads, 8 chains each

typedef float fvec4 __attribute__((ext_vector_type(4)));

__global__ __launch_bounds__(256) void a_kernel(const float* __restrict__ nu,
                                                const float* __restrict__ th,
                                                const float* __restrict__ dts,
                                                float* __restrict__ Ar,
                                                float* __restrict__ Ai) {
    int i = blockIdx.x * 256 + threadIdx.x;
    if (i >= BB * LL * ASLAB) return;
    int bl = i / ASLAB;
    float dt = dts[bl];
    float decay = expf(-nu[i] * dt);
    float s, c;
    sincosf(th[i] * dt, &s, &c);
    Ar[i] = decay * c;
    Ai[i] = decay * s;
}

__device__ __forceinline__ fvec4 ntload4(const float* p) {
    return __builtin_nontemporal_load(reinterpret_cast<const fvec4*>(p));
}
__device__ __forceinline__ void ntstore4(float* p, fvec4 v) {
    __builtin_nontemporal_store(v, reinterpret_cast<fvec4*>(p));
}

template<bool PRE>
__global__ __launch_bounds__(256) void scan_kernel(const float* __restrict__ ur,
                                                   const float* __restrict__ ui,
                                                   const float* __restrict__ Ar,
                                                   const float* __restrict__ Ai,
                                                   const float* __restrict__ nu,
                                                   const float* __restrict__ th,
                                                   const float* __restrict__ dts,
                                                   float* __restrict__ out) {
    int t = blockIdx.x * 256 + threadIdx.x;   // exact grid: NTH threads
    int b = t / (RR * CC * QG);
    int rem = t - b * (RR * CC * QG);
    int rc = rem / QG;
    int q = (rem - rc * QG) * 4;              // 0..1172, multiple of 4
    int w0 = q % WF;

    int a_off[4];
    #pragma unroll
    for (int j = 0; j < 4; ++j) {
        int wj = w0 + j; if (wj >= WF) wj -= WF;
        a_off[j] = rc * WF + wj;
    }
    const int chain0 = rc * HW + q;           // lower-half chain base within slab

    float h0r[4] = {0,0,0,0}, h0i[4] = {0,0,0,0};
    float h1r[4] = {0,0,0,0}, h1i[4] = {0,0,0,0};

    // ---- prologue: load l = 0 ----
    int base0 = b * LL * SLAB + chain0;
    fvec4 cxr0 = ntload4(ur + base0);
    fvec4 cxi0 = ntload4(ui + base0);
    fvec4 cxr1 = ntload4(ur + base0 + HALF);
    fvec4 cxi1 = ntload4(ui + base0 + HALF);
    float car[4], cai[4];
    {
        int ab = b * LL * ASLAB;
        if (PRE) {
            #pragma unroll
            for (int j = 0; j < 4; ++j) { car[j] = Ar[ab + a_off[j]]; cai[j] = Ai[ab + a_off[j]]; }
        } else {
            float dt = dts[b * LL];
            #pragma unroll
            for (int j = 0; j < 4; ++j) {
                float d = __expf(-nu[ab + a_off[j]] * dt);
                float s, c; __sincosf(th[ab + a_off[j]] * dt, &s, &c);
                car[j] = d * c; cai[j] = d * s;
            }
        }
    }

    #pragma unroll
    for (int l = 0; l < LL; ++l) {
        int bl = b * LL + l;
        int cbase = bl * SLAB + chain0;

        // ---- prefetch l+1 ----
        fvec4 nxr0, nxi0, nxr1, nxi1;
        float nar[4], nai[4];
        if (l + 1 < LL) {
            int nb = cbase + SLAB;
            nxr0 = ntload4(ur + nb);
            nxi0 = ntload4(ui + nb);
            nxr1 = ntload4(ur + nb + HALF);
            nxi1 = ntload4(ui + nb + HALF);
            int ab = (bl + 1) * ASLAB;
            if (PRE) {
                #pragma unroll
                for (int j = 0; j < 4; ++j) { nar[j] = Ar[ab + a_off[j]]; nai[j] = Ai[ab + a_off[j]]; }
            } else {
                float dt = dts[bl + 1];
                #pragma unroll
                for (int j = 0; j < 4; ++j) {
                    float d = __expf(-nu[ab + a_off[j]] * dt);
                    float s, c; __sincosf(th[ab + a_off[j]] * dt, &s, &c);
                    nar[j] = d * c; nai[j] = d * s;
                }
            }
        }

        // ---- recurrence for both h-halves ----
        float x0r[4] = {cxr0.x, cxr0.y, cxr0.z, cxr0.w};
        float x0i[4] = {cxi0.x, cxi0.y, cxi0.z, cxi0.w};
        float x1r[4] = {cxr1.x, cxr1.y, cxr1.z, cxr1.w};
        float x1i[4] = {cxi1.x, cxi1.y, cxi1.z, cxi1.w};
        #pragma unroll
        for (int j = 0; j < 4; ++j) {
            float nr0 = car[j] * h0r[j] - cai[j] * h0i[j] + x0r[j];
            float ni0 = car[j] * h0i[j] + cai[j] * h0r[j] + x0i[j];
            h0r[j] = nr0; h0i[j] = ni0;
            float nr1 = car[j] * h1r[j] - cai[j] * h1i[j] + x1r[j];
            float ni1 = car[j] * h1i[j] + cai[j] * h1r[j] + x1i[j];
            h1r[j] = nr1; h1i[j] = ni1;
        }

        // ---- store l ----
        fvec4 s0r = {h0r[0], h0r[1], h0r[2], h0r[3]};
        fvec4 s1r = {h1r[0], h1r[1], h1r[2], h1r[3]};
        fvec4 s0i = {h0i[0], h0i[1], h0i[2], h0i[3]};
        fvec4 s1i = {h1i[0], h1i[1], h1i[2], h1i[3]};
        ntstore4(out + cbase,                   s0r);
        ntstore4(out + cbase + HALF,            s1r);
        ntstore4(out + OUT_HALF + cbase,        s0i);
        ntstore4(out + OUT_HALF + cbase + HALF, s1i);

        // ---- rotate pipeline ----
        if (l + 1 < LL) {
            cxr0 = nxr0; cxi0 = nxi0; cxr1 = nxr1; cxi1 = nxi1;
            #pragma unroll
            for (int j = 0; j < 4; ++j) { car[j] = nar[j]; cai[j] = nai[j]; }
        }
    }
}

extern "C" void kernel_launch(void* const* d_in, const int* in_sizes, int n_in,
                              void* d_out, int out_size, void* d_ws, size_t ws_size,
                              hipStream_t stream) {
    const float* nu  = (const float*)d_in[0];
    const float* th  = (const float*)d_in[1];
    const float* dts = (const float*)d_in[2];
    const float* ur  = (const float*)d_in[3];
    const float* ui  = (const float*)d_in[4];
    float* out = (float*)d_out;

    const size_t a_elems = (size_t)BB * LL * ASLAB;          // 602112
    const bool use_ws = ws_size >= a_elems * 2 * sizeof(float);
    float* Ar = (float*)d_ws;
    float* Ai = Ar + a_elems;

    if (use_ws) {
        int na = (int)a_elems;
        a_kernel<<<(na + 255) / 256, 256, 0, stream>>>(nu, th, dts, Ar, Ai);
        scan_kernel<true><<<NTH / 256, 256, 0, stream>>>(ur, ui, Ar, Ai, nu, th, dts, out);
    } else {
        scan_kernel<false><<<NTH / 256, 256, 0, stream>>>(ur, ui, nullptr, nullptr, nu, th, dts, out);
    }
}

// Round 4
// 84.116 us; speedup vs baseline: 1.3732x; 1.3732x over previous
//
#include <hip/hip_runtime.h>

#define BB 2
#define LL 24
#define RR 8
#define CC 32
#define HH 48
#define WF 49
#define HW (HH*WF)            // 2352
#define ASLAB (RR*CC*WF)      // 12544  (A elements per (b,l))
#define SLAB (RR*CC*HH*WF)    // 602112 (u elements per (b,l))
#define OUT_HALF (BB*LL*SLAB) // 28901376
#define NCH (BB*SLAB)         // 1204224 independent chains
#define NTHREADS (NCH/4)      // 301056 (each thread owns 4 consecutive chains)

typedef float fvec4 __attribute__((ext_vector_type(4)));

__global__ __launch_bounds__(256) void a_kernel(const float* __restrict__ nu,
                                                const float* __restrict__ th,
                                                const float* __restrict__ dts,
                                                float* __restrict__ Ar,
                                                float* __restrict__ Ai) {
    int i = blockIdx.x * 256 + threadIdx.x;
    if (i >= BB * LL * ASLAB) return;
    int bl = i / ASLAB;             // b*L + l
    float dt = dts[bl];
    float decay = expf(-nu[i] * dt);
    float s, c;
    sincosf(th[i] * dt, &s, &c);
    Ar[i] = decay * c;
    Ai[i] = decay * s;
}

__device__ __forceinline__ void ntstore4(float* p, float a, float b, float c, float d) {
    fvec4 v = {a, b, c, d};
    __builtin_nontemporal_store(v, reinterpret_cast<fvec4*>(p));
}

template<bool PRE>
__global__ __launch_bounds__(256) void scan_kernel(const float* __restrict__ ur,
                                                   const float* __restrict__ ui,
                                                   const float* __restrict__ Ar,
                                                   const float* __restrict__ Ai,
                                                   const float* __restrict__ nu,
                                                   const float* __restrict__ th,
                                                   const float* __restrict__ dts,
                                                   float* __restrict__ out) {
    int t = blockIdx.x * 256 + threadIdx.x;   // 0 .. NTHREADS-1 (exact grid)
    int c4 = t * 4;                           // first of 4 consecutive chains
    int b = c4 / SLAB;
    int rest = c4 - b * SLAB;                 // multiple of 4, < SLAB
    int rc = rest / HW;                       // r*C + c   (A group)
    int hw = rest - rc * HW;                  // h*WF + w; hw+3 < HW since HW%4==0
    int w0 = hw % WF;

    int a_off[4];
    #pragma unroll
    for (int j = 0; j < 4; ++j) {
        int wj = w0 + j; if (wj >= WF) wj -= WF;   // w wraps within same rc (h+1)
        a_off[j] = rc * WF + wj;
    }

    float hr[4] = {0.f, 0.f, 0.f, 0.f};
    float hi[4] = {0.f, 0.f, 0.f, 0.f};

    for (int l = 0; l < LL; ++l) {
        int bl = b * LL + l;
        int base = bl * SLAB + rest;          // < 28.9M, fits int
        float4 xr = *reinterpret_cast<const float4*>(ur + base);
        float4 xi = *reinterpret_cast<const float4*>(ui + base);

        int ab = bl * ASLAB;
        float ar[4], ai[4];
        if (PRE) {
            #pragma unroll
            for (int j = 0; j < 4; ++j) {
                ar[j] = Ar[ab + a_off[j]];
                ai[j] = Ai[ab + a_off[j]];
            }
        } else {
            float dt = dts[bl];
            #pragma unroll
            for (int j = 0; j < 4; ++j) {
                float d = __expf(-nu[ab + a_off[j]] * dt);
                float s, c;
                __sincosf(th[ab + a_off[j]] * dt, &s, &c);
                ar[j] = d * c; ai[j] = d * s;
            }
        }

        float xrv[4] = {xr.x, xr.y, xr.z, xr.w};
        float xiv[4] = {xi.x, xi.y, xi.z, xi.w};
        #pragma unroll
        for (int j = 0; j < 4; ++j) {
            float nr = ar[j] * hr[j] - ai[j] * hi[j] + xrv[j];
            float ni = ar[j] * hi[j] + ai[j] * hr[j] + xiv[j];
            hr[j] = nr; hi[j] = ni;
        }

        ntstore4(out + base,            hr[0], hr[1], hr[2], hr[3]);
        ntstore4(out + OUT_HALF + base, hi[0], hi[1], hi[2], hi[3]);
    }
}

extern "C" void kernel_launch(void* const* d_in, const int* in_sizes, int n_in,
                              void* d_out, int out_size, void* d_ws, size_t ws_size,
                              hipStream_t stream) {
    const float* nu  = (const float*)d_in[0];   // (B,L,R,C,Wf)
    const float* th  = (const float*)d_in[1];   // (B,L,R,C,Wf)
    const float* dts = (const float*)d_in[2];   // (B,L)
    const float* ur  = (const float*)d_in[3];   // (B,L,R,C,H,Wf)
    const float* ui  = (const float*)d_in[4];   // (B,L,R,C,H,Wf)
    float* out = (float*)d_out;                 // (2,B,L,R,C,H,Wf) f32

    const size_t a_elems = (size_t)BB * LL * ASLAB;          // 602112
    const bool use_ws = ws_size >= a_elems * 2 * sizeof(float);
    float* Ar = (float*)d_ws;
    float* Ai = Ar + a_elems;

    if (use_ws) {
        int na = (int)a_elems;
        a_kernel<<<(na + 255) / 256, 256, 0, stream>>>(nu, th, dts, Ar, Ai);
        scan_kernel<true><<<NTHREADS / 256, 256, 0, stream>>>(ur, ui, Ar, Ai, nu, th, dts, out);
    } else {
        scan_kernel<false><<<NTHREADS / 256, 256, 0, stream>>>(ur, ui, nullptr, nullptr, nu, th, dts, out);
    }
}

// Round 5
// 83.962 us; speedup vs baseline: 1.3758x; 1.0018x over previous
//
#include <hip/hip_runtime.h>

#define BB 2
#define LL 24
#define RR 8
#define CC 32
#define HH 48
#define WF 49
#define HW (HH*WF)            // 2352
#define ASLAB (RR*CC*WF)      // 12544  (A elements per (b,l))
#define SLAB (RR*CC*HH*WF)    // 602112 (u elements per (b,l))
#define OUT_HALF (BB*LL*SLAB) // 28901376
#define NCH (BB*SLAB)         // 1204224 independent chains
#define NTHREADS (NCH/4)      // 301056 (each thread owns 4 consecutive chains)

typedef float fvec4 __attribute__((ext_vector_type(4)));

__global__ __launch_bounds__(256) void a_kernel(const float* __restrict__ nu,
                                                const float* __restrict__ th,
                                                const float* __restrict__ dts,
                                                float* __restrict__ Ar,
                                                float* __restrict__ Ai) {
    int i = blockIdx.x * 256 + threadIdx.x;
    if (i >= BB * LL * ASLAB) return;
    int bl = i / ASLAB;             // b*L + l
    float dt = dts[bl];
    float decay = expf(-nu[i] * dt);
    float s, c;
    sincosf(th[i] * dt, &s, &c);
    Ar[i] = decay * c;
    Ai[i] = decay * s;
}

__device__ __forceinline__ void ntstore4(float* p, float a, float b, float c, float d) {
    fvec4 v = {a, b, c, d};
    __builtin_nontemporal_store(v, reinterpret_cast<fvec4*>(p));
}

__global__ __launch_bounds__(256) void scan_kernel(const float* __restrict__ ur,
                                                   const float* __restrict__ ui,
                                                   const float* __restrict__ Ar,
                                                   const float* __restrict__ Ai,
                                                   float* __restrict__ out) {
    int t = blockIdx.x * 256 + threadIdx.x;   // 0 .. NTHREADS-1 (exact grid)
    int c4 = t * 4;                           // first of 4 consecutive chains
    int b = c4 / SLAB;
    int rest = c4 - b * SLAB;                 // multiple of 4, < SLAB
    int rc = rest / HW;                       // r*C + c   (A group)
    int hw = rest - rc * HW;                  // h*WF + w; hw+3 < HW since HW%4==0
    int w0 = hw % WF;

    int a_off[4];
    #pragma unroll
    for (int j = 0; j < 4; ++j) {
        int wj = w0 + j; if (wj >= WF) wj -= WF;   // w wraps within same rc (h+1)
        a_off[j] = rc * WF + wj;
    }

    float hr[4] = {0.f, 0.f, 0.f, 0.f};
    float hi[4] = {0.f, 0.f, 0.f, 0.f};

    // ---- prologue: load l = 0 (u first: longest latency) ----
    int base0 = b * LL * SLAB + rest;
    int ab0 = b * LL * ASLAB;
    float4 cxr = *reinterpret_cast<const float4*>(ur + base0);
    float4 cxi = *reinterpret_cast<const float4*>(ui + base0);
    float car[4], cai[4];
    #pragma unroll
    for (int j = 0; j < 4; ++j) {
        car[j] = Ar[ab0 + a_off[j]];
        cai[j] = Ai[ab0 + a_off[j]];
    }

    #pragma unroll
    for (int l = 0; l < LL; ++l) {
        int bl = b * LL + l;
        int base = bl * SLAB + rest;

        // ---- prefetch l+1 into fresh registers (issue before any wait) ----
        float4 nxr, nxi;
        float nar[4], nai[4];
        if (l + 1 < LL) {
            int nb = base + SLAB;
            nxr = *reinterpret_cast<const float4*>(ur + nb);
            nxi = *reinterpret_cast<const float4*>(ui + nb);
            int ab = (bl + 1) * ASLAB;
            #pragma unroll
            for (int j = 0; j < 4; ++j) {
                nar[j] = Ar[ab + a_off[j]];
                nai[j] = Ai[ab + a_off[j]];
            }
        }

        // ---- recurrence (waits only on l's loads, l+1's stay in flight) ----
        float xrv[4] = {cxr.x, cxr.y, cxr.z, cxr.w};
        float xiv[4] = {cxi.x, cxi.y, cxi.z, cxi.w};
        #pragma unroll
        for (int j = 0; j < 4; ++j) {
            float nr = car[j] * hr[j] - cai[j] * hi[j] + xrv[j];
            float ni = car[j] * hi[j] + cai[j] * hr[j] + xiv[j];
            hr[j] = nr; hi[j] = ni;
        }

        ntstore4(out + base,            hr[0], hr[1], hr[2], hr[3]);
        ntstore4(out + OUT_HALF + base, hi[0], hi[1], hi[2], hi[3]);

        // ---- rotate ----
        if (l + 1 < LL) {
            cxr = nxr; cxi = nxi;
            #pragma unroll
            for (int j = 0; j < 4; ++j) { car[j] = nar[j]; cai[j] = nai[j]; }
        }
    }
}

// Fallback (no workspace): recompute A inline per iteration.
__global__ __launch_bounds__(256) void scan_kernel_nows(const float* __restrict__ ur,
                                                        const float* __restrict__ ui,
                                                        const float* __restrict__ nu,
                                                        const float* __restrict__ th,
                                                        const float* __restrict__ dts,
                                                        float* __restrict__ out) {
    int t = blockIdx.x * 256 + threadIdx.x;
    int c4 = t * 4;
    int b = c4 / SLAB;
    int rest = c4 - b * SLAB;
    int rc = rest / HW;
    int hw = rest - rc * HW;
    int w0 = hw % WF;

    int a_off[4];
    #pragma unroll
    for (int j = 0; j < 4; ++j) {
        int wj = w0 + j; if (wj >= WF) wj -= WF;
        a_off[j] = rc * WF + wj;
    }

    float hr[4] = {0.f, 0.f, 0.f, 0.f};
    float hi[4] = {0.f, 0.f, 0.f, 0.f};

    for (int l = 0; l < LL; ++l) {
        int bl = b * LL + l;
        int base = bl * SLAB + rest;
        float4 xr = *reinterpret_cast<const float4*>(ur + base);
        float4 xi = *reinterpret_cast<const float4*>(ui + base);
        int ab = bl * ASLAB;
        float dt = dts[bl];
        float ar[4], ai[4];
        #pragma unroll
        for (int j = 0; j < 4; ++j) {
            float d = __expf(-nu[ab + a_off[j]] * dt);
            float s, c;
            __sincosf(th[ab + a_off[j]] * dt, &s, &c);
            ar[j] = d * c; ai[j] = d * s;
        }
        float xrv[4] = {xr.x, xr.y, xr.z, xr.w};
        float xiv[4] = {xi.x, xi.y, xi.z, xi.w};
        #pragma unroll
        for (int j = 0; j < 4; ++j) {
            float nr = ar[j] * hr[j] - ai[j] * hi[j] + xrv[j];
            float ni = ar[j] * hi[j] + ai[j] * hr[j] + xiv[j];
            hr[j] = nr; hi[j] = ni;
        }
        ntstore4(out + base,            hr[0], hr[1], hr[2], hr[3]);
        ntstore4(out + OUT_HALF + base, hi[0], hi[1], hi[2], hi[3]);
    }
}

extern "C" void kernel_launch(void* const* d_in, const int* in_sizes, int n_in,
                              void* d_out, int out_size, void* d_ws, size_t ws_size,
                              hipStream_t stream) {
    const float* nu  = (const float*)d_in[0];   // (B,L,R,C,Wf)
    const float* th  = (const float*)d_in[1];   // (B,L,R,C,Wf)
    const float* dts = (const float*)d_in[2];   // (B,L)
    const float* ur  = (const float*)d_in[3];   // (B,L,R,C,H,Wf)
    const float* ui  = (const float*)d_in[4];   // (B,L,R,C,H,Wf)
    float* out = (float*)d_out;                 // (2,B,L,R,C,H,Wf) f32

    const size_t a_elems = (size_t)BB * LL * ASLAB;          // 602112
    const bool use_ws = ws_size >= a_elems * 2 * sizeof(float);
    float* Ar = (float*)d_ws;
    float* Ai = Ar + a_elems;

    if (use_ws) {
        int na = (int)a_elems;
        a_kernel<<<(na + 255) / 256, 256, 0, stream>>>(nu, th, dts, Ar, Ai);
        scan_kernel<<<NTHREADS / 256, 256, 0, stream>>>(ur, ui, Ar, Ai, out);
    } else {
        scan_kernel_nows<<<NTHREADS / 256, 256, 0, stream>>>(ur, ui, nu, th, dts, out);
    }
}